// Round 3
// baseline (8325.493 us; speedup 1.0000x reference)
//
#include <hip/hip_runtime.h>

#define NWG   256
#define NTHR  512
#define TSEQ  512
#define HID   1024
#define NCLS  32000
#define KP1   2056   // padded LDS row stride (elements), layer 1 (K=2048); per-16-lane-phase 2-way (free)
#define KP0   1544   // padded LDS row stride (elements), layer 0 (K=1536)
#define RP    44     // red row stride (f32): per-phase 2-way (free)
#define F0IDX 288    // flag0: # completed layer-0 iterations
#define F1IDX 608    // flag1: # completed layer-1 iterations
#define SPIN_GUARD 50000000u

typedef __attribute__((ext_vector_type(8))) short short8;
typedef __attribute__((ext_vector_type(4))) float floatx4;

struct AB { short8 a[4]; short8 b[2]; };

__device__ __forceinline__ unsigned short f2bf(float f) {
  union { float f; unsigned u; } c; c.f = f;
  unsigned r = c.u + 0x7fffu + ((c.u >> 16) & 1u);
  return (unsigned short)(r >> 16);
}
__device__ __forceinline__ float sigmoidf_(float x) {
  x = fminf(30.f, fmaxf(-30.f, x));
  return 1.f / (1.f + __expf(-x));
}
__device__ __forceinline__ float tanhf_(float x) {
  x = fminf(15.f, fmaxf(-15.f, x));
  float e = __expf(2.f * x);
  return (e - 1.f) / (e + 1.f);
}
__device__ __forceinline__ void st_u32_agent(unsigned* p, unsigned v) {
  __hip_atomic_store(p, v, __ATOMIC_RELAXED, __HIP_MEMORY_SCOPE_AGENT);
}

__device__ __forceinline__ void mfma8(const AB& f, floatx4 (&acc)[4][2]) {
#pragma unroll
  for (int mt = 0; mt < 4; ++mt)
#pragma unroll
    for (int nt = 0; nt < 2; ++nt)
      acc[mt][nt] = __builtin_amdgcn_mfma_f32_16x16x32_bf16(f.a[mt], f.b[nt], acc[mt][nt], 0, 0, 0);
}

// Deep-prefetch GEMM phase: issue ALL NKT fragments' loads (A global, B LDS),
// then the MFMA burst — single latency exposure instead of NKT serial groups.
template <int NKT, int KPAD>
__device__ __forceinline__ void gemm_deep(
    int kb, int keo, int lm,
    const unsigned short* const (&ab)[4],
    const unsigned short* wl, floatx4 (&acc)[4][2])
{
  AB f[NKT];
#pragma unroll
  for (int kt = 0; kt < NKT; ++kt) {
    const int off = kb + kt * 32 + keo;
#pragma unroll
    for (int nt = 0; nt < 2; ++nt)
      f[kt].b[nt] = *reinterpret_cast<const short8*>(wl + (nt * 16 + lm) * KPAD + off);
#pragma unroll
    for (int mt = 0; mt < 4; ++mt)
      f[kt].a[mt] = *reinterpret_cast<const short8*>(ab[mt] + off);
  }
#pragma unroll
  for (int kt = 0; kt < NKT; ++kt) mfma8(f[kt], acc);
}

// Layer-0 x-phase: gather A straight from emb (f32) with inline f2bf; no xbuf,
// no cross-WG staging dependency.
template <int NKT, int KPAD>
__device__ __forceinline__ void gemm_emb(
    int kb, int keo, int lm, int t,
    const int* __restrict__ feat, const float* __restrict__ emb,
    const unsigned short* wl, floatx4 (&acc)[4][2])
{
  const float* er[4];
#pragma unroll
  for (int mt = 0; mt < 4; ++mt)
    er[mt] = emb + (size_t)feat[(mt * 16 + lm) * TSEQ + t] * 512;
  AB f[NKT];
#pragma unroll
  for (int kt = 0; kt < NKT; ++kt) {
    const int off = kb + kt * 32 + keo;
#pragma unroll
    for (int nt = 0; nt < 2; ++nt)
      f[kt].b[nt] = *reinterpret_cast<const short8*>(wl + (nt * 16 + lm) * KPAD + off);
#pragma unroll
    for (int mt = 0; mt < 4; ++mt) {
      const float4 v0 = *(const float4*)(er[mt] + off);
      const float4 v1 = *(const float4*)(er[mt] + off + 4);
      short8 a;
      a[0] = (short)f2bf(v0.x); a[1] = (short)f2bf(v0.y);
      a[2] = (short)f2bf(v0.z); a[3] = (short)f2bf(v0.w);
      a[4] = (short)f2bf(v1.x); a[5] = (short)f2bf(v1.y);
      a[6] = (short)f2bf(v1.z); a[7] = (short)f2bf(v1.w);
      f[kt].a[mt] = a;
    }
  }
#pragma unroll
  for (int kt = 0; kt < NKT; ++kt) mfma8(f[kt], acc);
}

__global__ void __launch_bounds__(NTHR, 1)
lstm_kernel(const int* __restrict__ feat,
            const float* __restrict__ emb,
            const float* __restrict__ wih0, const float* __restrict__ whh0,
            const float* __restrict__ bih0, const float* __restrict__ bhh0,
            const float* __restrict__ wih1, const float* __restrict__ whh1,
            const float* __restrict__ bih1, const float* __restrict__ bhh1,
            const float* __restrict__ fcw, const float* __restrict__ fcb,
            float* __restrict__ out,
            unsigned* __restrict__ bar)
{
  const int tid  = threadIdx.x;
  const int wg   = blockIdx.x;
  const int wave = tid >> 6;
  const int lane = tid & 63;
  const int quad = lane >> 4;
  const int lm   = lane & 15;
  const int keo  = quad * 8;

  // bf16 scratch inside d_out (f32 [64,32000] = 8.19 MB); FC overwrites at end.
  unsigned short* sc = (unsigned short*)out;
  unsigned short* h0 = sc;              // 8-slot ring x [64][1024]  (layer-0 out)
  unsigned short* h1 = sc + 524288;     // 2 x [64][1024]
  unsigned short* lh = sc + 655360;     // [64][1024]

  const int layer = (wg >= 128) ? 1 : 0;
  const int wl_id = wg & 127;
  const int jb = wl_id * 8;             // this WG owns H-columns [jb, jb+8)

  __shared__ unsigned short wlds[32 * KP1];  // this WG's weights, bf16
  __shared__ float red[4][32][RP];           // K-split partials
  __shared__ int   sl[64];
  __shared__ unsigned sdone[2];              // per-parity "cell stores drained" count

  if (tid < 2) sdone[tid] = 0;

  // ---- one-time: weights f32 -> bf16 -> LDS  (rows r: gate=r>>3, col=jb+(r&7)) ----
  {
    const float* wih = layer ? wih1 : wih0;
    const float* whh = layer ? whh1 : whh0;
    const int KX   = layer ? 1024 : 512;
    const int KTOT = layer ? 2048 : 1536;
    const int KPAD = layer ? KP1 : KP0;
    for (int r = 0; r < 32; ++r) {
      const int gr = (r >> 3) * HID + jb + (r & 7);
      for (int e4 = tid; e4 < (KTOT >> 2); e4 += NTHR) {
        const int k = e4 * 4;
        float4 v = (k < KX) ? *(const float4*)(wih + (size_t)gr * KX + k)
                            : *(const float4*)(whh + (size_t)gr * 1024 + (k - KX));
        ushort4 u; u.x = f2bf(v.x); u.y = f2bf(v.y); u.z = f2bf(v.z); u.w = f2bf(v.w);
        *(ushort4*)(wlds + r * KPAD + k) = u;
      }
    }
    if (layer && tid < 64) {   // seq_lens
      int cnt = 0;
      const int* fr = feat + tid * TSEQ;
      for (int k = 0; k < TSEQ; k += 4)
        cnt += (fr[k] != 31999) + (fr[k + 1] != 31999) +
               (fr[k + 2] != 31999) + (fr[k + 3] != 31999);
      int v = cnt - 1; if (v < 0) v = 0;
      sl[tid] = v;
    }
  }
  __syncthreads();

  // ---- per-cell-thread persistent state (tid<256: b = half*32 + (tid>>3), jl = tid&7)
  float bsum[4];
  float cv[2] = {0.f, 0.f};
  int   slv[2] = {0, 0};
  const int jl_c = tid & 7;
  const int bl_c = tid >> 3;     // 0..31 for tid<256
  if (tid < 256) {
    const float* bih = layer ? bih1 : bih0;
    const float* bhh = layer ? bhh1 : bhh0;
    const int gj = jb + jl_c;
#pragma unroll
    for (int g = 0; g < 4; ++g) bsum[g] = bih[g * HID + gj] + bhh[g * HID + gj];
    if (layer) { slv[0] = sl[bl_c]; slv[1] = sl[32 + bl_c]; }
  }

  // ---- spin primitive (watchdog-guarded) ----
  auto spin_ge = [&](int idx, unsigned need) -> unsigned {
    unsigned g = 0, v;
    while ((v = __hip_atomic_load(&bar[idx], __ATOMIC_RELAXED, __HIP_MEMORY_SCOPE_AGENT)) < need) {
      __builtin_amdgcn_s_sleep(1);
      if (++g > SPIN_GUARD) break;
    }
    return v;
  };

  // ---- reduction + fused cell update (proven structure, RP=44) ----
  auto reduce_cell = [&](floatx4 (&acc)[4][2], unsigned short* hw, int t) {
#pragma unroll
    for (int h = 0; h < 2; ++h) {
      if (wave < 4) {
#pragma unroll
        for (int mi = 0; mi < 2; ++mi)
#pragma unroll
          for (int nt = 0; nt < 2; ++nt)
#pragma unroll
            for (int r = 0; r < 4; ++r)
              red[wave][mi * 16 + quad * 4 + r][nt * 16 + lm] = acc[2 * h + mi][nt][r];
      }
      __syncthreads();
      if (wave >= 4) {
#pragma unroll
        for (int mi = 0; mi < 2; ++mi)
#pragma unroll
          for (int nt = 0; nt < 2; ++nt)
#pragma unroll
            for (int r = 0; r < 4; ++r)
              red[wave - 4][mi * 16 + quad * 4 + r][nt * 16 + lm] += acc[2 * h + mi][nt][r];
      }
      __syncthreads();
      if (tid < 256) {
        const int b = h * 32 + bl_c;
        float g0 = bsum[0], g1 = bsum[1], g2 = bsum[2], g3 = bsum[3];
#pragma unroll
        for (int v = 0; v < 4; ++v) {
          g0 += red[v][bl_c][jl_c];
          g1 += red[v][bl_c][8 + jl_c];
          g2 += red[v][bl_c][16 + jl_c];
          g3 += red[v][bl_c][24 + jl_c];
        }
        const float ig = sigmoidf_(g0);
        const float fg = sigmoidf_(g1);
        const float gg = tanhf_(g2);
        const float og = sigmoidf_(g3);
        const float cn = fg * cv[h] + ig * gg;
        cv[h] = cn;
        const float hn = og * tanhf_(cn);
        unsigned my = f2bf(hn);
        unsigned ov = (unsigned)__shfl_xor((int)my, 1, 64);
        if ((tid & 1) == 0) {
          const unsigned packed = my | (ov << 16);
          st_u32_agent((unsigned*)(hw + b * HID + jb + jl_c), packed);
          if (layer && t == slv[h])
            st_u32_agent((unsigned*)(lh + b * HID + jb + jl_c), packed);
        }
      }
      if (h == 0) __syncthreads();
    }
  };

  // ---- delegated arrive: waves 0-3 drain + LDS-signal; wave 7 does the 2-level
  //      LLC arrive while the other waves proceed into the next x-phase.
  auto finish_step = [&](int t, int cbase, int c2, int cflag) {
    if (wave < 4) {
      __builtin_amdgcn_s_waitcnt(0);   // drain this wave's h/lh agent stores
      if (lane == 0)
        __hip_atomic_fetch_add(&sdone[t & 1], 1u, __ATOMIC_RELAXED, __HIP_MEMORY_SCOPE_WORKGROUP);
    } else if (wave == 7) {
      if (lane == 0) {
        unsigned g = 0;
        while (__hip_atomic_load(&sdone[t & 1], __ATOMIC_RELAXED, __HIP_MEMORY_SCOPE_WORKGROUP) < 4u)
          if (++g > SPIN_GUARD) break;
        __hip_atomic_store(&sdone[t & 1], 0u, __ATOMIC_RELAXED, __HIP_MEMORY_SCOPE_WORKGROUP);
        const unsigned r = (unsigned)t + 1u;
        unsigned old = __hip_atomic_fetch_add(&bar[cbase + (wg & 7) * 32], 1u,
                                              __ATOMIC_RELAXED, __HIP_MEMORY_SCOPE_AGENT);
        if (old == r * 16u - 1u) {
          unsigned mo = __hip_atomic_fetch_add(&bar[c2], 1u,
                                               __ATOMIC_RELAXED, __HIP_MEMORY_SCOPE_AGENT);
          if (mo == r * 8u - 1u)
            __hip_atomic_store(&bar[cflag], r, __ATOMIC_RELAXED, __HIP_MEMORY_SCOPE_AGENT);
        }
      }
    }
  };

  if (!layer) {
    // =========================== LAYER 0 ===========================
    unsigned seenOwn = 0, seenRing = 0;   // tid0-only caches
    for (int t = 0; t < TSEQ; ++t) {
      floatx4 acc[4][2];
#pragma unroll
      for (int mt = 0; mt < 4; ++mt)
#pragma unroll
        for (int nt = 0; nt < 2; ++nt)
          acc[mt][nt] = (floatx4){0.f, 0.f, 0.f, 0.f};

      // x-phase: emb gather GEMM, K=[0,512), no cross-WG dependency.
      // Overlaps own-domain stragglers finishing iteration t-1.
      gemm_emb<2, KP0>(wave * 64, keo, lm, t, feat, emb, wlds, acc);

      // own barrier: h0(t-1) ready; ring guard: L1 consumed h0(t-8)
      if (tid == 0) {
        bool fen = false;
        if (seenOwn < (unsigned)t) { seenOwn = spin_ge(F0IDX, (unsigned)t); fen = true; }
        const unsigned nr = (t >= 8) ? (unsigned)(t - 7) : 0u;
        if (seenRing < nr) seenRing = spin_ge(F1IDX, nr);   // anti-overwrite only: no fence needed
        if (fen) __builtin_amdgcn_fence(__ATOMIC_ACQUIRE, "agent");
      }
      __syncthreads();

      // h-phase: K=[512,1536) from h0(t-1), deep prefetch
      const unsigned short* hb[4];
      const unsigned short* h0r = h0 + (size_t)((t + 7) & 7) * 65536;
#pragma unroll
      for (int mt = 0; mt < 4; ++mt) hb[mt] = h0r + (mt * 16 + lm) * HID - 512;
      gemm_deep<4, KP0>(512 + wave * 128, keo, lm, hb, wlds, acc);

      unsigned short* hw = h0 + (size_t)(t & 7) * 65536;
      reduce_cell(acc, hw, t);
      finish_step(t, 0, 256, F0IDX);     // publishes flag0 = t+1
    }
  } else {
    // =========================== LAYER 1 ===========================
    unsigned seenX = 0;     // per-wave (all lanes uniform) cache of flag0
    unsigned seenOwn = 0;   // tid0-only cache of flag1
    for (int t = 0; t < TSEQ; ++t) {
      // cross dep: h0(t) ready (flag0 >= t+1). Per-wave, register-cached:
      // free in steady state (L0 runs up to 8 iterations ahead).
      const unsigned needX = (unsigned)(t + 1);
      if (seenX < needX) {
        unsigned v = 0;
        if (lane == 0) v = spin_ge(F0IDX, needX);
        v = (unsigned)__shfl((int)v, 0, 64);
        seenX = v;
        __builtin_amdgcn_fence(__ATOMIC_ACQUIRE, "agent");
      }

      floatx4 acc[4][2];
#pragma unroll
      for (int mt = 0; mt < 4; ++mt)
#pragma unroll
        for (int nt = 0; nt < 2; ++nt)
          acc[mt][nt] = (floatx4){0.f, 0.f, 0.f, 0.f};

      // x-phase: K=[0,1024) from h0(t), deep prefetch. Overlaps stragglers.
      const unsigned short* xb[4];
      const unsigned short* h0r = h0 + (size_t)(t & 7) * 65536;
#pragma unroll
      for (int mt = 0; mt < 4; ++mt) xb[mt] = h0r + (mt * 16 + lm) * HID;
      gemm_deep<4, KP1>(wave * 128, keo, lm, xb, wlds, acc);

      // own barrier: h1(t-1) ready (flag1 >= t)
      if (tid == 0) {
        if (seenOwn < (unsigned)t) {
          seenOwn = spin_ge(F1IDX, (unsigned)t);
          __builtin_amdgcn_fence(__ATOMIC_ACQUIRE, "agent");
        }
      }
      __syncthreads();

      // h-phase: K=[1024,2048) from h1(t-1), deep prefetch
      const unsigned short* hb[4];
      const unsigned short* h1r = h1 + (size_t)((t + 1) & 1) * 65536;
#pragma unroll
      for (int mt = 0; mt < 4; ++mt) hb[mt] = h1r + (mt * 16 + lm) * HID - 1024;
      gemm_deep<4, KP1>(1024 + wave * 128, keo, lm, hb, wlds, acc);

      unsigned short* hw = h1 + (size_t)(t & 1) * 65536;
      reduce_cell(acc, hw, t);
      finish_step(t, 320, 576, F1IDX);   // publishes flag1 = t+1
    }
  }

  // ---- full-grid join (round-based, both domains; 8 groups x 32 WGs) ----
  auto sync_all = [&](unsigned r) {
    __builtin_amdgcn_s_waitcnt(0);
    __syncthreads();
    if (tid == 0) {
      unsigned old = __hip_atomic_fetch_add(&bar[640 + (wg & 7) * 32], 1u,
                                            __ATOMIC_RELAXED, __HIP_MEMORY_SCOPE_AGENT);
      if (old == r * 32u - 1u) {
        unsigned mo = __hip_atomic_fetch_add(&bar[896], 1u,
                                             __ATOMIC_RELAXED, __HIP_MEMORY_SCOPE_AGENT);
        if (mo == r * 8u - 1u)
          __hip_atomic_store(&bar[928], r, __ATOMIC_RELAXED, __HIP_MEMORY_SCOPE_AGENT);
      }
      spin_ge(928, r);
      __builtin_amdgcn_fence(__ATOMIC_ACQUIRE, "agent");
    }
    __syncthreads();
  };

  sync_all(1);   // all lh stores visible before FC reads

  // ===== FC: pred[64, 32000] = last_h @ fc_w^T + fc_b  (fcw f32 -> bf16 on the fly)
  const int colbase = wg * 125;                 // 256 * 125 = 32000
  const int col  = colbase + wave * 16 + lm;    // 8 waves x 16 = 128 cols
  const int colc = (col < NCLS) ? col : (NCLS - 1);
  floatx4 facc[4];
  {
    const unsigned short* ab[4];
#pragma unroll
    for (int mt = 0; mt < 4; ++mt) ab[mt] = lh + (mt * 16 + lm) * HID;
    const float* bb = fcw + (size_t)colc * HID;

#pragma unroll
    for (int mt = 0; mt < 4; ++mt) facc[mt] = (floatx4){0.f, 0.f, 0.f, 0.f};

    short8 a0[4], a1[4], b0, b1;
    auto ld = [&](short8 (&A)[4], short8& B, int kbase) {
      const int off = kbase + keo;
      float4 v0 = *(const float4*)(bb + off);
      float4 v1 = *(const float4*)(bb + off + 4);
      short8 bv;
      bv[0] = (short)f2bf(v0.x); bv[1] = (short)f2bf(v0.y);
      bv[2] = (short)f2bf(v0.z); bv[3] = (short)f2bf(v0.w);
      bv[4] = (short)f2bf(v1.x); bv[5] = (short)f2bf(v1.y);
      bv[6] = (short)f2bf(v1.z); bv[7] = (short)f2bf(v1.w);
      B = bv;
#pragma unroll
      for (int mt = 0; mt < 4; ++mt)
        A[mt] = *reinterpret_cast<const short8*>(ab[mt] + off);
    };
    ld(a0, b0, 0);
#pragma unroll
    for (int kt = 0; kt < 30; kt += 2) {
      ld(a1, b1, (kt + 1) * 32);
#pragma unroll
      for (int mt = 0; mt < 4; ++mt)
        facc[mt] = __builtin_amdgcn_mfma_f32_16x16x32_bf16(a0[mt], b0, facc[mt], 0, 0, 0);
      ld(a0, b0, (kt + 2) * 32);
#pragma unroll
      for (int mt = 0; mt < 4; ++mt)
        facc[mt] = __builtin_amdgcn_mfma_f32_16x16x32_bf16(a1[mt], b1, facc[mt], 0, 0, 0);
    }
    ld(a1, b1, 31 * 32);
#pragma unroll
    for (int mt = 0; mt < 4; ++mt)
      facc[mt] = __builtin_amdgcn_mfma_f32_16x16x32_bf16(a0[mt], b0, facc[mt], 0, 0, 0);
#pragma unroll
    for (int mt = 0; mt < 4; ++mt)
      facc[mt] = __builtin_amdgcn_mfma_f32_16x16x32_bf16(a1[mt], b1, facc[mt], 0, 0, 0);
  }

  sync_all(2);   // everyone done reading lh before stores clobber scratch

  if (col < colbase + 125) {
    const float bias = fcb[col];
#pragma unroll
    for (int mt = 0; mt < 4; ++mt)
#pragma unroll
      for (int r = 0; r < 4; ++r) {
        const int row = mt * 16 + quad * 4 + r;
        out[(size_t)row * NCLS + col] = facc[mt][r] + bias;
      }
  }
}

extern "C" void kernel_launch(void* const* d_in, const int* in_sizes, int n_in,
                              void* d_out, int out_size, void* d_ws, size_t ws_size,
                              hipStream_t stream) {
  (void)in_sizes; (void)n_in; (void)out_size; (void)ws_size;
  const int*   feat = (const int*)d_in[0];
  const float* emb  = (const float*)d_in[1];
  const float* wih0 = (const float*)d_in[2];
  const float* whh0 = (const float*)d_in[3];
  const float* bih0 = (const float*)d_in[4];
  const float* bhh0 = (const float*)d_in[5];
  const float* wih1 = (const float*)d_in[6];
  const float* whh1 = (const float*)d_in[7];
  const float* bih1 = (const float*)d_in[8];
  const float* bhh1 = (const float*)d_in[9];
  const float* fcw  = (const float*)d_in[10];
  const float* fcb  = (const float*)d_in[11];
  float*       out  = (float*)d_out;
  unsigned*    bar  = (unsigned*)d_ws;

  // zero bf16 scratch inside d_out (h0 ring x8, h1 x2, lh) + barrier words
  hipMemsetAsync(d_out, 0, 1441792, stream);
  hipMemsetAsync(d_ws, 0, 8192, stream);

  void* args[] = { &feat, &emb, &wih0, &whh0, &bih0, &bhh0, &wih1, &whh1,
                   &bih1, &bhh1, &fcw, &fcb, &out, &bar };
  hipLaunchCooperativeKernel((const void*)lstm_kernel, dim3(NWG), dim3(NTHR),
                             args, 0, stream);
}

// Round 4
// 6074.070 us; speedup vs baseline: 1.3707x; 1.3707x over previous
//
#include <hip/hip_runtime.h>

#define NWG   256
#define NTHR  512
#define TSEQ  512
#define HID   1024
#define NCLS  32000
#define KP1   2056   // padded LDS row stride (elements), layer 1 (K=2048)
#define KP0   1544   // padded LDS row stride (elements), layer 0 (K=1536)
#define RP    44     // red row stride (f32): per-16-lane-phase 2-way (free)
#define F0IDX 288    // flag0 = 1 (prologue) + # completed layer-0 iterations
#define F1IDX 608    // flag1 = # completed layer-1 iterations
#define SPIN_GUARD 50000000u

typedef __attribute__((ext_vector_type(8))) short short8;
typedef __attribute__((ext_vector_type(4))) float floatx4;

struct AB { short8 a[4]; short8 b[2]; };

__device__ __forceinline__ unsigned short f2bf(float f) {
  union { float f; unsigned u; } c; c.f = f;
  unsigned r = c.u + 0x7fffu + ((c.u >> 16) & 1u);
  return (unsigned short)(r >> 16);
}
__device__ __forceinline__ float sigmoidf_(float x) {
  x = fminf(30.f, fmaxf(-30.f, x));
  return 1.f / (1.f + __expf(-x));
}
__device__ __forceinline__ float tanhf_(float x) {
  x = fminf(15.f, fmaxf(-15.f, x));
  float e = __expf(2.f * x);
  return (e - 1.f) / (e + 1.f);
}
__device__ __forceinline__ void st_u32_agent(unsigned* p, unsigned v) {
  __hip_atomic_store(p, v, __ATOMIC_RELAXED, __HIP_MEMORY_SCOPE_AGENT);
}

__device__ __forceinline__ void mfma8(const AB& f, floatx4 (&acc)[4][2]) {
#pragma unroll
  for (int mt = 0; mt < 4; ++mt)
#pragma unroll
    for (int nt = 0; nt < 2; ++nt)
      acc[mt][nt] = __builtin_amdgcn_mfma_f32_16x16x32_bf16(f.a[mt], f.b[nt], acc[mt][nt], 0, 0, 0);
}

// Single-source K-slice GEMM, pair-pipelined (2 load groups in flight) —
// the round-2-proven structure.  ab pre-shifted so ab+off is valid for off in slice.
template <int NKT, int KPAD>
__device__ __forceinline__ void gemm_part(
    int kb, int keo, int lm,
    const unsigned short* const (&ab)[4],
    const unsigned short* wl, floatx4 (&acc)[4][2])
{
  AB f0, f1;
  auto ld = [&](AB& f, int kt) {
    const int off = kb + kt * 32 + keo;
#pragma unroll
    for (int nt = 0; nt < 2; ++nt)
      f.b[nt] = *reinterpret_cast<const short8*>(wl + (nt * 16 + lm) * KPAD + off);
#pragma unroll
    for (int mt = 0; mt < 4; ++mt)
      f.a[mt] = *reinterpret_cast<const short8*>(ab[mt] + off);
  };
  ld(f0, 0);
#pragma unroll
  for (int kt = 0; kt + 2 < NKT; kt += 2) {
    ld(f1, kt + 1);
    mfma8(f0, acc);
    ld(f0, kt + 2);
    mfma8(f1, acc);
  }
  ld(f1, NKT - 1);
  mfma8(f0, acc);
  mfma8(f1, acc);
}

__global__ void __launch_bounds__(NTHR, 1)
lstm_kernel(const int* __restrict__ feat,
            const float* __restrict__ emb,
            const float* __restrict__ wih0, const float* __restrict__ whh0,
            const float* __restrict__ bih0, const float* __restrict__ bhh0,
            const float* __restrict__ wih1, const float* __restrict__ whh1,
            const float* __restrict__ bih1, const float* __restrict__ bhh1,
            const float* __restrict__ fcw, const float* __restrict__ fcb,
            float* __restrict__ out,
            unsigned* __restrict__ bar)
{
  const int tid  = threadIdx.x;
  const int wg   = blockIdx.x;
  const int wave = tid >> 6;
  const int lane = tid & 63;
  const int quad = lane >> 4;
  const int lm   = lane & 15;
  const int keo  = quad * 8;

  // bf16 scratch inside d_out (f32 [64,32000] = 8.19 MB); FC overwrites at end.
  unsigned short* sc   = (unsigned short*)out;
  unsigned short* h0   = sc;              // 8-slot ring x [64][1024]  (layer-0 out)
  unsigned short* h1   = sc + 524288;     // 2 x [64][1024]
  unsigned short* lh   = sc + 655360;     // [64][1024]
  unsigned short* xbuf = sc + 720896;     // 4-slot ring x [64][512]  (staged x, bf16)

  const int layer = (wg >= 128) ? 1 : 0;
  const int wl_id = wg & 127;
  const int jb = wl_id * 8;               // this WG owns H-columns [jb, jb+8)

  __shared__ unsigned short wlds[32 * KP1];  // this WG's weights, bf16
  __shared__ float red[4][32][RP];           // K-split partials
  __shared__ int   sl[64];
  __shared__ unsigned sdone[2];              // per-parity "cell stores drained" count

  if (tid < 2) sdone[tid] = 0;

  // ---- one-time: weights f32 -> bf16 -> LDS  (rows r: gate=r>>3, col=jb+(r&7)) ----
  {
    const float* wih = layer ? wih1 : wih0;
    const float* whh = layer ? whh1 : whh0;
    const int KX   = layer ? 1024 : 512;
    const int KTOT = layer ? 2048 : 1536;
    const int KPAD = layer ? KP1 : KP0;
    for (int r = 0; r < 32; ++r) {
      const int gr = (r >> 3) * HID + jb + (r & 7);
      for (int e4 = tid; e4 < (KTOT >> 2); e4 += NTHR) {
        const int k = e4 * 4;
        float4 v = (k < KX) ? *(const float4*)(wih + (size_t)gr * KX + k)
                            : *(const float4*)(whh + (size_t)gr * 1024 + (k - KX));
        ushort4 u; u.x = f2bf(v.x); u.y = f2bf(v.y); u.z = f2bf(v.z); u.w = f2bf(v.w);
        *(ushort4*)(wlds + r * KPAD + k) = u;
      }
    }
    if (layer && tid < 64) {   // seq_lens
      int cnt = 0;
      const int* fr = feat + tid * TSEQ;
      for (int k = 0; k < TSEQ; k += 4)
        cnt += (fr[k] != 31999) + (fr[k + 1] != 31999) +
               (fr[k + 2] != 31999) + (fr[k + 3] != 31999);
      int v = cnt - 1; if (v < 0) v = 0;
      sl[tid] = v;
    }
  }
  __syncthreads();

  // ---- per-cell-thread persistent state (tid<256: b = half*32 + (tid>>3), jl = tid&7)
  float bsum[4];
  float cv[2] = {0.f, 0.f};
  int   slv[2] = {0, 0};
  const int jl_c = tid & 7;
  const int bl_c = tid >> 3;     // 0..31 for tid<256
  if (tid < 256) {
    const float* bih = layer ? bih1 : bih0;
    const float* bhh = layer ? bhh1 : bhh0;
    const int gj = jb + jl_c;
#pragma unroll
    for (int g = 0; g < 4; ++g) bsum[g] = bih[g * HID + gj] + bhh[g * HID + gj];
    if (layer) { slv[0] = sl[bl_c]; slv[1] = sl[32 + bl_c]; }
  }

  // ---- spin primitive (watchdog-guarded; returns observed value) ----
  auto spin_ge = [&](int idx, unsigned need) -> unsigned {
    unsigned g = 0, v;
    while ((v = __hip_atomic_load(&bar[idx], __ATOMIC_RELAXED, __HIP_MEMORY_SCOPE_AGENT)) < need) {
      __builtin_amdgcn_s_sleep(1);
      if (++g > SPIN_GUARD) break;
    }
    return v;
  };

  // ---- reduction + fused cell update (round-2-proven) ----
  auto reduce_cell = [&](floatx4 (&acc)[4][2], unsigned short* hw, int t) {
#pragma unroll
    for (int h = 0; h < 2; ++h) {
      if (wave < 4) {
#pragma unroll
        for (int mi = 0; mi < 2; ++mi)
#pragma unroll
          for (int nt = 0; nt < 2; ++nt)
#pragma unroll
            for (int r = 0; r < 4; ++r)
              red[wave][mi * 16 + quad * 4 + r][nt * 16 + lm] = acc[2 * h + mi][nt][r];
      }
      __syncthreads();
      if (wave >= 4) {
#pragma unroll
        for (int mi = 0; mi < 2; ++mi)
#pragma unroll
          for (int nt = 0; nt < 2; ++nt)
#pragma unroll
            for (int r = 0; r < 4; ++r)
              red[wave - 4][mi * 16 + quad * 4 + r][nt * 16 + lm] += acc[2 * h + mi][nt][r];
      }
      __syncthreads();
      if (tid < 256) {
        const int b = h * 32 + bl_c;
        float g0 = bsum[0], g1 = bsum[1], g2 = bsum[2], g3 = bsum[3];
#pragma unroll
        for (int v = 0; v < 4; ++v) {
          g0 += red[v][bl_c][jl_c];
          g1 += red[v][bl_c][8 + jl_c];
          g2 += red[v][bl_c][16 + jl_c];
          g3 += red[v][bl_c][24 + jl_c];
        }
        const float ig = sigmoidf_(g0);
        const float fg = sigmoidf_(g1);
        const float gg = tanhf_(g2);
        const float og = sigmoidf_(g3);
        const float cn = fg * cv[h] + ig * gg;
        cv[h] = cn;
        const float hn = og * tanhf_(cn);
        unsigned my = f2bf(hn);
        unsigned ov = (unsigned)__shfl_xor((int)my, 1, 64);
        if ((tid & 1) == 0) {
          const unsigned packed = my | (ov << 16);
          st_u32_agent((unsigned*)(hw + b * HID + jb + jl_c), packed);
          if (layer && t == slv[h])
            st_u32_agent((unsigned*)(lh + b * HID + jb + jl_c), packed);
        }
      }
      if (h == 0) __syncthreads();
    }
  };

  // ---- delegated arrive: waves 0-3 drain + LDS-signal; wave 7 does the 2-level
  //      LLC arrive while other waves proceed into the next x-phase.
  auto finish_step = [&](int par, unsigned r, int cbase, int c2, int cflag) {
    if (wave < 4) {
      __builtin_amdgcn_s_waitcnt(0);   // drain h/lh/xbuf agent stores of this wave
      if (lane == 0)
        __hip_atomic_fetch_add(&sdone[par], 1u, __ATOMIC_RELAXED, __HIP_MEMORY_SCOPE_WORKGROUP);
    } else if (wave == 7 && lane == 0) {
      unsigned g = 0;
      while (__hip_atomic_load(&sdone[par], __ATOMIC_RELAXED, __HIP_MEMORY_SCOPE_WORKGROUP) < 4u)
        if (++g > SPIN_GUARD) break;
      __hip_atomic_store(&sdone[par], 0u, __ATOMIC_RELAXED, __HIP_MEMORY_SCOPE_WORKGROUP);
      unsigned old = __hip_atomic_fetch_add(&bar[cbase + (wg & 7) * 32], 1u,
                                            __ATOMIC_RELAXED, __HIP_MEMORY_SCOPE_AGENT);
      if (old == r * 16u - 1u) {           // last of my XCD subgroup
        unsigned mo = __hip_atomic_fetch_add(&bar[c2], 1u,
                                             __ATOMIC_RELAXED, __HIP_MEMORY_SCOPE_AGENT);
        if (mo == r * 8u - 1u)             // last subgroup -> publish
          __hip_atomic_store(&bar[cflag], r, __ATOMIC_RELAXED, __HIP_MEMORY_SCOPE_AGENT);
      }
    }
  };

  if (!layer) {
    // =========================== LAYER 0 ===========================
    // prologue: stage x(0), x(1) (bf16 broadcast via xbuf); L0-domain barrier r=1
    if (tid < 256) {
      const int b = wl_id >> 1;
      const int off = (wl_id & 1) * 256 + tid;
#pragma unroll
      for (int tt = 0; tt < 2; ++tt) {
        unsigned xv = f2bf(emb[(size_t)feat[b * TSEQ + tt] * 512 + off]);
        unsigned ov = (unsigned)__shfl_xor((int)xv, 1, 64);
        if ((tid & 1) == 0)
          st_u32_agent((unsigned*)(xbuf + tt * 32768 + b * 512 + off), xv | (ov << 16));
      }
    }
    __builtin_amdgcn_s_waitcnt(0);
    __syncthreads();
    if (tid == 0) {
      unsigned old = __hip_atomic_fetch_add(&bar[(wg & 7) * 32], 1u,
                                            __ATOMIC_RELAXED, __HIP_MEMORY_SCOPE_AGENT);
      if (old == 15u) {
        unsigned mo = __hip_atomic_fetch_add(&bar[256], 1u,
                                             __ATOMIC_RELAXED, __HIP_MEMORY_SCOPE_AGENT);
        if (mo == 7u)
          __hip_atomic_store(&bar[F0IDX], 1u, __ATOMIC_RELAXED, __HIP_MEMORY_SCOPE_AGENT);
      }
      spin_ge(F0IDX, 1u);
      __builtin_amdgcn_fence(__ATOMIC_ACQUIRE, "agent");
    }
    __syncthreads();

    unsigned seenOwn = 1, seenRing = 0;   // tid0-only caches
    for (int t = 0; t < TSEQ; ++t) {
      // stage x(t+2) into slot (t+2)&3 (visibility: covered by step t+1's own-fence)
      if (t + 2 < TSEQ && tid < 256) {
        const int b = wl_id >> 1;
        const int off = (wl_id & 1) * 256 + tid;
        unsigned xv = f2bf(emb[(size_t)feat[b * TSEQ + (t + 2)] * 512 + off]);
        unsigned ov = (unsigned)__shfl_xor((int)xv, 1, 64);
        if ((tid & 1) == 0)
          st_u32_agent((unsigned*)(xbuf + ((t + 2) & 3) * 32768 + b * 512 + off), xv | (ov << 16));
      }

      floatx4 acc[4][2];
#pragma unroll
      for (int mt = 0; mt < 4; ++mt)
#pragma unroll
        for (int nt = 0; nt < 2; ++nt)
          acc[mt][nt] = (floatx4){0.f, 0.f, 0.f, 0.f};

      // x-phase: K=[0,512) from xbuf slot t&3 — zero sync at step top.
      // Overlaps own-domain stragglers + arrive/flag propagation of step t-1.
      {
        const unsigned short* ab[4];
        const unsigned short* xq = xbuf + (size_t)(t & 3) * 32768;
#pragma unroll
        for (int mt = 0; mt < 4; ++mt) ab[mt] = xq + (mt * 16 + lm) * 512;
        gemm_part<2, KP0>(wave * 64, keo, lm, ab, wlds, acc);
      }

      // own barrier: h0(t-1) ready (flag0 >= t+1); ring: L1 consumed h0(t-8)
      if (tid == 0) {
        bool fen = false;
        const unsigned needO = (unsigned)(t + 1);
        if (seenOwn < needO) { seenOwn = spin_ge(F0IDX, needO); fen = true; }
        if (t >= 8) {
          const unsigned nr = (unsigned)(t - 7);
          if (seenRing < nr) seenRing = spin_ge(F1IDX, nr);   // anti-overwrite only
        }
        if (fen) __builtin_amdgcn_fence(__ATOMIC_ACQUIRE, "agent");
      }
      __syncthreads();

      // h-phase: K=[512,1536) from h0(t-1)
      {
        const unsigned short* hb[4];
        const unsigned short* h0r = h0 + (size_t)((t + 7) & 7) * 65536;
#pragma unroll
        for (int mt = 0; mt < 4; ++mt) hb[mt] = h0r + (mt * 16 + lm) * HID - 512;
        gemm_part<4, KP0>(512 + wave * 128, keo, lm, hb, wlds, acc);
      }

      reduce_cell(acc, h0 + (size_t)(t & 7) * 65536, t);
      finish_step(t & 1, (unsigned)(t + 2), 0, 256, F0IDX);   // flag0 = t+2
    }
  } else {
    // =========================== LAYER 1 ===========================
    unsigned seenX = 0;      // per-wave cache of flag0 (uniform across lanes)
    unsigned seenOwn = 0;    // tid0-only cache of flag1
    for (int t = 0; t < TSEQ; ++t) {
      // cross dep: h0(t) ready (flag0 >= t+2); register-cached, free in steady state
      const unsigned needX = (unsigned)(t + 2);
      if (seenX < needX) {
        unsigned v = 0;
        if (lane == 0) v = spin_ge(F0IDX, needX);
        v = (unsigned)__shfl((int)v, 0, 64);
        seenX = v;
        __builtin_amdgcn_fence(__ATOMIC_ACQUIRE, "agent");
      }

      floatx4 acc[4][2];
#pragma unroll
      for (int mt = 0; mt < 4; ++mt)
#pragma unroll
        for (int nt = 0; nt < 2; ++nt)
          acc[mt][nt] = (floatx4){0.f, 0.f, 0.f, 0.f};

      // x-phase: K=[0,1024) from h0(t) — overlaps own-domain stragglers
      {
        const unsigned short* ab[4];
        const unsigned short* h0r = h0 + (size_t)(t & 7) * 65536;
#pragma unroll
        for (int mt = 0; mt < 4; ++mt) ab[mt] = h0r + (mt * 16 + lm) * HID;
        gemm_part<4, KP1>(wave * 128, keo, lm, ab, wlds, acc);
      }

      // own barrier: h1(t-1) ready (flag1 >= t)
      if (tid == 0) {
        const unsigned needO = (unsigned)t;
        if (seenOwn < needO) {
          seenOwn = spin_ge(F1IDX, needO);
          __builtin_amdgcn_fence(__ATOMIC_ACQUIRE, "agent");
        }
      }
      __syncthreads();

      // h-phase: K=[1024,2048) from h1(t-1)
      {
        const unsigned short* hb[4];
        const unsigned short* h1r = h1 + (size_t)((t + 1) & 1) * 65536;
#pragma unroll
        for (int mt = 0; mt < 4; ++mt) hb[mt] = h1r + (mt * 16 + lm) * HID - 1024;
        gemm_part<4, KP1>(1024 + wave * 128, keo, lm, hb, wlds, acc);
      }

      reduce_cell(acc, h1 + (size_t)(t & 1) * 65536, t);
      finish_step(t & 1, (unsigned)(t + 1), 320, 576, F1IDX);  // flag1 = t+1
    }
  }

  // ---- full-grid join (round-based; 8 groups x 32 WGs) ----
  auto sync_all = [&](unsigned r) {
    __builtin_amdgcn_s_waitcnt(0);
    __syncthreads();
    if (tid == 0) {
      unsigned old = __hip_atomic_fetch_add(&bar[640 + (wg & 7) * 32], 1u,
                                            __ATOMIC_RELAXED, __HIP_MEMORY_SCOPE_AGENT);
      if (old == r * 32u - 1u) {
        unsigned mo = __hip_atomic_fetch_add(&bar[896], 1u,
                                             __ATOMIC_RELAXED, __HIP_MEMORY_SCOPE_AGENT);
        if (mo == r * 8u - 1u)
          __hip_atomic_store(&bar[928], r, __ATOMIC_RELAXED, __HIP_MEMORY_SCOPE_AGENT);
      }
      spin_ge(928, r);
      __builtin_amdgcn_fence(__ATOMIC_ACQUIRE, "agent");
    }
    __syncthreads();
  };

  sync_all(1);   // all lh stores visible before FC reads

  // ===== FC: pred[64, 32000] = last_h @ fc_w^T + fc_b  (fcw f32 -> bf16 on the fly)
  const int colbase = wg * 125;                 // 256 * 125 = 32000
  const int col  = colbase + wave * 16 + lm;    // 8 waves x 16 = 128 cols
  const int colc = (col < NCLS) ? col : (NCLS - 1);
  floatx4 facc[4];
  {
    const unsigned short* ab[4];
#pragma unroll
    for (int mt = 0; mt < 4; ++mt) ab[mt] = lh + (mt * 16 + lm) * HID;
    const float* bb = fcw + (size_t)colc * HID;

#pragma unroll
    for (int mt = 0; mt < 4; ++mt) facc[mt] = (floatx4){0.f, 0.f, 0.f, 0.f};

    short8 a0[4], a1[4], b0, b1;
    auto ld = [&](short8 (&A)[4], short8& B, int kbase) {
      const int off = kbase + keo;
      float4 v0 = *(const float4*)(bb + off);
      float4 v1 = *(const float4*)(bb + off + 4);
      short8 bv;
      bv[0] = (short)f2bf(v0.x); bv[1] = (short)f2bf(v0.y);
      bv[2] = (short)f2bf(v0.z); bv[3] = (short)f2bf(v0.w);
      bv[4] = (short)f2bf(v1.x); bv[5] = (short)f2bf(v1.y);
      bv[6] = (short)f2bf(v1.z); bv[7] = (short)f2bf(v1.w);
      B = bv;
#pragma unroll
      for (int mt = 0; mt < 4; ++mt)
        A[mt] = *reinterpret_cast<const short8*>(ab[mt] + off);
    };
    ld(a0, b0, 0);
#pragma unroll
    for (int kt = 0; kt < 30; kt += 2) {
      ld(a1, b1, (kt + 1) * 32);
#pragma unroll
      for (int mt = 0; mt < 4; ++mt)
        facc[mt] = __builtin_amdgcn_mfma_f32_16x16x32_bf16(a0[mt], b0, facc[mt], 0, 0, 0);
      ld(a0, b0, (kt + 2) * 32);
#pragma unroll
      for (int mt = 0; mt < 4; ++mt)
        facc[mt] = __builtin_amdgcn_mfma_f32_16x16x32_bf16(a1[mt], b1, facc[mt], 0, 0, 0);
    }
    ld(a1, b1, 31 * 32);
#pragma unroll
    for (int mt = 0; mt < 4; ++mt)
      facc[mt] = __builtin_amdgcn_mfma_f32_16x16x32_bf16(a0[mt], b0, facc[mt], 0, 0, 0);
#pragma unroll
    for (int mt = 0; mt < 4; ++mt)
      facc[mt] = __builtin_amdgcn_mfma_f32_16x16x32_bf16(a1[mt], b1, facc[mt], 0, 0, 0);
  }

  sync_all(2);   // everyone done reading lh before stores clobber scratch

  if (col < colbase + 125) {
    const float bias = fcb[col];
#pragma unroll
    for (int mt = 0; mt < 4; ++mt)
#pragma unroll
      for (int r = 0; r < 4; ++r) {
        const int row = mt * 16 + quad * 4 + r;
        out[(size_t)row * NCLS + col] = facc[mt][r] + bias;
      }
  }
}

extern "C" void kernel_launch(void* const* d_in, const int* in_sizes, int n_in,
                              void* d_out, int out_size, void* d_ws, size_t ws_size,
                              hipStream_t stream) {
  (void)in_sizes; (void)n_in; (void)out_size; (void)ws_size;
  const int*   feat = (const int*)d_in[0];
  const float* emb  = (const float*)d_in[1];
  const float* wih0 = (const float*)d_in[2];
  const float* whh0 = (const float*)d_in[3];
  const float* bih0 = (const float*)d_in[4];
  const float* bhh0 = (const float*)d_in[5];
  const float* wih1 = (const float*)d_in[6];
  const float* whh1 = (const float*)d_in[7];
  const float* bih1 = (const float*)d_in[8];
  const float* bhh1 = (const float*)d_in[9];
  const float* fcw  = (const float*)d_in[10];
  const float* fcb  = (const float*)d_in[11];
  float*       out  = (float*)d_out;
  unsigned*    bar  = (unsigned*)d_ws;

  // zero bf16 scratch inside d_out (h0 ring x8, h1 x2, lh, xbuf x4) + barrier words
  hipMemsetAsync(d_out, 0, 1703936, stream);
  hipMemsetAsync(d_ws, 0, 8192, stream);

  void* args[] = { &feat, &emb, &wih0, &whh0, &bih0, &bhh0, &wih1, &whh1,
                   &bih1, &bhh1, &fcw, &fcb, &out, &bar };
  hipLaunchCooperativeKernel((const void*)lstm_kernel, dim3(NWG), dim3(NTHR),
                             args, 0, stream);
}

// Round 6
// 5841.923 us; speedup vs baseline: 1.4251x; 1.0397x over previous
//
#include <hip/hip_runtime.h>

#define NWG   256
#define NTHR  512
#define TSEQ  512
#define HID   1024
#define NCLS  32000
#define KP1   2056   // padded LDS row stride (elements), layer 1 (K=2048)
#define KP0   1544   // padded LDS row stride (elements), layer 0 (K=1536)
#define RP    44     // red row stride (f32): per-16-lane-phase 2-way (free)
#define PROG0 256    // per-WG progress, layer 0: bar[PROG0 + wl*4]  (1 + steps done)
#define PROG1 1024   // per-WG progress, layer 1: bar[PROG1 + wl*4]  (steps done)
#define FJBASE 1600  // final join arrive counters (8 groups x 32 WGs)
#define FJL2   1856
#define FJFLAG 1888
#define SPIN_GUARD 10000000u   // LDS / final-join spins (~0.3 s max)
#define SCAN_GUARD 1000000u    // LLC scan spins (~0.3 s max); on expiry -> saturate
#define SATUR 0x7FFFFFFFu      // saturating "give up" value: all later waits skip

typedef __attribute__((ext_vector_type(8))) short short8;
typedef __attribute__((ext_vector_type(4))) float floatx4;

struct AB { short8 a[4]; short8 b[2]; };

__device__ __forceinline__ unsigned short f2bf(float f) {
  union { float f; unsigned u; } c; c.f = f;
  unsigned r = c.u + 0x7fffu + ((c.u >> 16) & 1u);
  return (unsigned short)(r >> 16);
}
__device__ __forceinline__ float sigmoidf_(float x) {
  x = fminf(30.f, fmaxf(-30.f, x));
  return 1.f / (1.f + __expf(-x));
}
__device__ __forceinline__ float tanhf_(float x) {
  x = fminf(15.f, fmaxf(-15.f, x));
  float e = __expf(2.f * x);
  return (e - 1.f) / (e + 1.f);
}
__device__ __forceinline__ void st_u32_agent(unsigned* p, unsigned v) {
  __hip_atomic_store(p, v, __ATOMIC_RELAXED, __HIP_MEMORY_SCOPE_AGENT);
}
__device__ __forceinline__ unsigned ld_u32_agent(const unsigned* p) {
  return __hip_atomic_load(p, __ATOMIC_RELAXED, __HIP_MEMORY_SCOPE_AGENT);
}

__device__ __forceinline__ void mfma8(const AB& f, floatx4 (&acc)[4][2]) {
#pragma unroll
  for (int mt = 0; mt < 4; ++mt)
#pragma unroll
    for (int nt = 0; nt < 2; ++nt)
      acc[mt][nt] = __builtin_amdgcn_mfma_f32_16x16x32_bf16(f.a[mt], f.b[nt], acc[mt][nt], 0, 0, 0);
}

// Single-source K-slice GEMM, pair-pipelined — the round-2-proven structure.
template <int NKT, int KPAD>
__device__ __forceinline__ void gemm_part(
    int kb, int keo, int lm,
    const unsigned short* const (&ab)[4],
    const unsigned short* wl, floatx4 (&acc)[4][2])
{
  AB f0, f1;
  auto ld = [&](AB& f, int kt) {
    const int off = kb + kt * 32 + keo;
#pragma unroll
    for (int nt = 0; nt < 2; ++nt)
      f.b[nt] = *reinterpret_cast<const short8*>(wl + (nt * 16 + lm) * KPAD + off);
#pragma unroll
    for (int mt = 0; mt < 4; ++mt)
      f.a[mt] = *reinterpret_cast<const short8*>(ab[mt] + off);
  };
  ld(f0, 0);
#pragma unroll
  for (int kt = 0; kt + 2 < NKT; kt += 2) {
    ld(f1, kt + 1);
    mfma8(f0, acc);
    ld(f0, kt + 2);
    mfma8(f1, acc);
  }
  ld(f1, NKT - 1);
  mfma8(f0, acc);
  mfma8(f1, acc);
}

__global__ void __launch_bounds__(NTHR, 1)
lstm_kernel(const int* __restrict__ feat,
            const float* __restrict__ emb,
            const float* __restrict__ wih0, const float* __restrict__ whh0,
            const float* __restrict__ bih0, const float* __restrict__ bhh0,
            const float* __restrict__ wih1, const float* __restrict__ whh1,
            const float* __restrict__ bih1, const float* __restrict__ bhh1,
            const float* __restrict__ fcw, const float* __restrict__ fcb,
            float* __restrict__ out,
            unsigned* __restrict__ bar)
{
  const int tid  = threadIdx.x;
  const int wg   = blockIdx.x;
  const int wave = tid >> 6;
  const int lane = tid & 63;
  const int quad = lane >> 4;
  const int lm   = lane & 15;
  const int keo  = quad * 8;

  // bf16 scratch inside d_out (f32 [64,32000] = 8.19 MB); FC overwrites at end.
  unsigned short* sc   = (unsigned short*)out;
  unsigned short* h0   = sc;              // 8-slot ring x [64][1024]  (layer-0 out)
  unsigned short* h1   = sc + 524288;     // 2 x [64][1024]
  unsigned short* lh   = sc + 655360;     // [64][1024]
  unsigned short* xbuf = sc + 720896;     // 4-slot ring x [64][512]  (staged x, bf16)

  const int layer = (wg >= 128) ? 1 : 0;
  const int wl_id = wg & 127;
  const int jb = wl_id * 8;               // this WG owns H-columns [jb, jb+8)

  __shared__ unsigned short wlds[32 * KP1];  // this WG's weights, bf16
  __shared__ float red[4][32][RP];           // K-split partials
  __shared__ int   sl[64];
  __shared__ unsigned sdone[2];              // per-parity "cell stores drained" count

  if (tid < 2) sdone[tid] = 0;

  // ---- one-time: weights f32 -> bf16 -> LDS  (rows r: gate=r>>3, col=jb+(r&7)) ----
  {
    const float* wih = layer ? wih1 : wih0;
    const float* whh = layer ? whh1 : whh0;
    const int KX   = layer ? 1024 : 512;
    const int KTOT = layer ? 2048 : 1536;
    const int KPAD = layer ? KP1 : KP0;
    for (int r = 0; r < 32; ++r) {
      const int gr = (r >> 3) * HID + jb + (r & 7);
      for (int e4 = tid; e4 < (KTOT >> 2); e4 += NTHR) {
        const int k = e4 * 4;
        float4 v = (k < KX) ? *(const float4*)(wih + (size_t)gr * KX + k)
                            : *(const float4*)(whh + (size_t)gr * 1024 + (k - KX));
        ushort4 u; u.x = f2bf(v.x); u.y = f2bf(v.y); u.z = f2bf(v.z); u.w = f2bf(v.w);
        *(ushort4*)(wlds + r * KPAD + k) = u;
      }
    }
    if (layer && tid < 64) {   // seq_lens
      int cnt = 0;
      const int* fr = feat + tid * TSEQ;
      for (int k = 0; k < TSEQ; k += 4)
        cnt += (fr[k] != 31999) + (fr[k + 1] != 31999) +
               (fr[k + 2] != 31999) + (fr[k + 3] != 31999);
      int v = cnt - 1; if (v < 0) v = 0;
      sl[tid] = v;
    }
  }
  __syncthreads();

  // ---- per-cell-thread persistent state (tid<256: b = half*32 + (tid>>3), jl = tid&7)
  float bsum[4];
  float cv[2] = {0.f, 0.f};
  int   slv[2] = {0, 0};
  const int jl_c = tid & 7;
  const int bl_c = tid >> 3;     // 0..31 for tid<256
  if (tid < 256) {
    const float* bih = layer ? bih1 : bih0;
    const float* bhh = layer ? bhh1 : bhh0;
    const int gj = jb + jl_c;
#pragma unroll
    for (int g = 0; g < 4; ++g) bsum[g] = bih[g * HID + gj] + bhh[g * HID + gj];
    if (layer) { slv[0] = sl[bl_c]; slv[1] = sl[32 + bl_c]; }
  }

  // ---- wave-cooperative scans over 128 per-WG progress words (no RMW, no
  //      contention: one LLC RTT per poll).  Return wave-min for caching.
  //      FAIL-FAST: on watchdog expiry return SATUR so all later waits skip
  //      (kernel then finishes quickly with wrong output instead of hanging).
  auto scan1 = [&](int base, unsigned need) -> unsigned {
    unsigned g = 0, a0, a1;
    bool dead = false;
    for (;;) {
      a0 = ld_u32_agent(&bar[base + lane * 4]);
      a1 = ld_u32_agent(&bar[base + (64 + lane) * 4]);
      if (__all(a0 >= need && a1 >= need)) break;
      __builtin_amdgcn_s_sleep(1);
      if (++g > SCAN_GUARD) { dead = true; break; }
    }
    if (dead) return SATUR;
    unsigned m = a0 < a1 ? a0 : a1;
#pragma unroll
    for (int off = 32; off; off >>= 1) {
      unsigned o = (unsigned)__shfl_xor((int)m, off, 64);
      m = o < m ? o : m;
    }
    return m;
  };
  auto scan2 = [&](int baseA, unsigned needA, int baseB, unsigned needB,
                   unsigned& minA, unsigned& minB) {
    unsigned g = 0, a0, a1, b0, b1;
    bool dead = false;
    for (;;) {
      a0 = ld_u32_agent(&bar[baseA + lane * 4]);
      a1 = ld_u32_agent(&bar[baseA + (64 + lane) * 4]);
      b0 = ld_u32_agent(&bar[baseB + lane * 4]);
      b1 = ld_u32_agent(&bar[baseB + (64 + lane) * 4]);
      if (__all(a0 >= needA && a1 >= needA && b0 >= needB && b1 >= needB)) break;
      __builtin_amdgcn_s_sleep(1);
      if (++g > SCAN_GUARD) { dead = true; break; }
    }
    if (dead) { minA = SATUR; minB = SATUR; return; }
    unsigned ma = a0 < a1 ? a0 : a1;
    unsigned mb = b0 < b1 ? b0 : b1;
#pragma unroll
    for (int off = 32; off; off >>= 1) {
      unsigned oa = (unsigned)__shfl_xor((int)ma, off, 64); ma = oa < ma ? oa : ma;
      unsigned ob = (unsigned)__shfl_xor((int)mb, off, 64); mb = ob < mb ? ob : mb;
    }
    minA = ma; minB = mb;
  };
  auto spin_ge = [&](int idx, unsigned need) {   // final-join only
    unsigned g = 0;
    while (ld_u32_agent(&bar[idx]) < need) {
      __builtin_amdgcn_s_sleep(1);
      if (++g > SPIN_GUARD) break;
    }
  };

  // ---- reduction + fused cell update (round-2-proven) ----
  auto reduce_cell = [&](floatx4 (&acc)[4][2], unsigned short* hw, int t) {
#pragma unroll
    for (int h = 0; h < 2; ++h) {
      if (wave < 4) {
#pragma unroll
        for (int mi = 0; mi < 2; ++mi)
#pragma unroll
          for (int nt = 0; nt < 2; ++nt)
#pragma unroll
            for (int r = 0; r < 4; ++r)
              red[wave][mi * 16 + quad * 4 + r][nt * 16 + lm] = acc[2 * h + mi][nt][r];
      }
      __syncthreads();
      if (wave >= 4) {
#pragma unroll
        for (int mi = 0; mi < 2; ++mi)
#pragma unroll
          for (int nt = 0; nt < 2; ++nt)
#pragma unroll
            for (int r = 0; r < 4; ++r)
              red[wave - 4][mi * 16 + quad * 4 + r][nt * 16 + lm] += acc[2 * h + mi][nt][r];
      }
      __syncthreads();
      if (tid < 256) {
        const int b = h * 32 + bl_c;
        float g0 = bsum[0], g1 = bsum[1], g2 = bsum[2], g3 = bsum[3];
#pragma unroll
        for (int v = 0; v < 4; ++v) {
          g0 += red[v][bl_c][jl_c];
          g1 += red[v][bl_c][8 + jl_c];
          g2 += red[v][bl_c][16 + jl_c];
          g3 += red[v][bl_c][24 + jl_c];
        }
        const float ig = sigmoidf_(g0);
        const float fg = sigmoidf_(g1);
        const float gg = tanhf_(g2);
        const float og = sigmoidf_(g3);
        const float cn = fg * cv[h] + ig * gg;
        cv[h] = cn;
        const float hn = og * tanhf_(cn);
        unsigned my = f2bf(hn);
        unsigned ov = (unsigned)__shfl_xor((int)my, 1, 64);
        if ((tid & 1) == 0) {
          const unsigned packed = my | (ov << 16);
          st_u32_agent((unsigned*)(hw + b * HID + jb + jl_c), packed);
          if (layer && t == slv[h])
            st_u32_agent((unsigned*)(lh + b * HID + jb + jl_c), packed);
        }
      }
      if (h == 0) __syncthreads();
    }
  };

  // ---- publish progress: waves 0-3 drain + LDS-signal; wave 7 plain-stores
  //      this WG's OWN progress word (no RMW, no cacheline contention).
  auto finish_step = [&](int par, unsigned r, int pbase) {
    if (wave < 4) {
      __builtin_amdgcn_s_waitcnt(0);   // drain h/lh/xbuf agent stores of this wave
      if (lane == 0)
        __hip_atomic_fetch_add(&sdone[par], 1u, __ATOMIC_RELAXED, __HIP_MEMORY_SCOPE_WORKGROUP);
    } else if (wave == 7 && lane == 0) {
      unsigned g = 0;
      while (__hip_atomic_load(&sdone[par], __ATOMIC_RELAXED, __HIP_MEMORY_SCOPE_WORKGROUP) < 4u)
        if (++g > SPIN_GUARD) break;
      __hip_atomic_store(&sdone[par], 0u, __ATOMIC_RELAXED, __HIP_MEMORY_SCOPE_WORKGROUP);
      st_u32_agent(&bar[pbase + wl_id * 4], r);
    }
  };

  if (!layer) {
    // =========================== LAYER 0 ===========================
    // prologue: stage x(0), x(1); publish prog0 = 1; wait domain; fence
    if (tid < 256) {
      const int b = wl_id >> 1;
      const int off = (wl_id & 1) * 256 + tid;
#pragma unroll
      for (int tt = 0; tt < 2; ++tt) {
        unsigned xv = f2bf(emb[(size_t)feat[b * TSEQ + tt] * 512 + off]);
        unsigned ov = (unsigned)__shfl_xor((int)xv, 1, 64);
        if ((tid & 1) == 0)
          st_u32_agent((unsigned*)(xbuf + tt * 32768 + b * 512 + off), xv | (ov << 16));
      }
    }
    __builtin_amdgcn_s_waitcnt(0);
    __syncthreads();
    if (wave == 7 && lane == 0) st_u32_agent(&bar[PROG0 + wl_id * 4], 1u);
    unsigned seenOwn = 1, seenRing = 0;   // wave-0 caches (uniform)
    if (wave == 0) {
      seenOwn = scan1(PROG0, 1u);
      __builtin_amdgcn_fence(__ATOMIC_ACQUIRE, "agent");
    }
    __syncthreads();

    for (int t = 0; t < TSEQ; ++t) {
      // stage x(t+2) into slot (t+2)&3 (visibility covered by step t+1's own-fence)
      if (t + 2 < TSEQ && tid < 256) {
        const int b = wl_id >> 1;
        const int off = (wl_id & 1) * 256 + tid;
        unsigned xv = f2bf(emb[(size_t)feat[b * TSEQ + (t + 2)] * 512 + off]);
        unsigned ov = (unsigned)__shfl_xor((int)xv, 1, 64);
        if ((tid & 1) == 0)
          st_u32_agent((unsigned*)(xbuf + ((t + 2) & 3) * 32768 + b * 512 + off), xv | (ov << 16));
      }

      floatx4 acc[4][2];
#pragma unroll
      for (int mt = 0; mt < 4; ++mt)
#pragma unroll
        for (int nt = 0; nt < 2; ++nt)
          acc[mt][nt] = (floatx4){0.f, 0.f, 0.f, 0.f};

      // x-phase: K=[0,512) from xbuf slot t&3 — zero sync at step top.
      {
        const unsigned short* ab[4];
        const unsigned short* xq = xbuf + (size_t)(t & 3) * 32768;
#pragma unroll
        for (int mt = 0; mt < 4; ++mt) ab[mt] = xq + (mt * 16 + lm) * 512;
        gemm_part<2, KP0>(wave * 64, keo, lm, ab, wlds, acc);
      }

      // own barrier: h0(t-1) ready (all prog0 >= t+1); ring: L1 consumed h0(t-8)
      if (wave == 0) {
        const unsigned needO = (unsigned)(t + 1);
        const unsigned needR = (t >= 8) ? (unsigned)(t - 7) : 0u;
        if (seenOwn < needO || seenRing < needR) {
          scan2(PROG0, needO, PROG1, needR, seenOwn, seenRing);
          __builtin_amdgcn_fence(__ATOMIC_ACQUIRE, "agent");
        }
      }
      __syncthreads();

      // h-phase: K=[512,1536) from h0(t-1)
      {
        const unsigned short* hb[4];
        const unsigned short* h0r = h0 + (size_t)((t + 7) & 7) * 65536;
#pragma unroll
        for (int mt = 0; mt < 4; ++mt) hb[mt] = h0r + (mt * 16 + lm) * HID - 512;
        gemm_part<4, KP0>(512 + wave * 128, keo, lm, hb, wlds, acc);
      }

      reduce_cell(acc, h0 + (size_t)(t & 7) * 65536, t);
      finish_step(t & 1, (unsigned)(t + 2), PROG0);   // prog0 = t+2
    }
  } else {
    // =========================== LAYER 1 ===========================
    unsigned seenX = 0;      // per-wave cache (uniform within wave)
    unsigned seenOwn = 0;    // wave-0 cache
    for (int t = 0; t < TSEQ; ++t) {
      // cross dep: h0(t) ready (all prog0 >= t+2); per-wave scan, cached by min
      const unsigned needX = (unsigned)(t + 2);
      if (seenX < needX) {
        seenX = scan1(PROG0, needX);
        __builtin_amdgcn_fence(__ATOMIC_ACQUIRE, "agent");
      }

      floatx4 acc[4][2];
#pragma unroll
      for (int mt = 0; mt < 4; ++mt)
#pragma unroll
        for (int nt = 0; nt < 2; ++nt)
          acc[mt][nt] = (floatx4){0.f, 0.f, 0.f, 0.f};

      // x-phase: K=[0,1024) from h0(t) — overlaps own-domain stragglers
      {
        const unsigned short* ab[4];
        const unsigned short* h0r = h0 + (size_t)(t & 7) * 65536;
#pragma unroll
        for (int mt = 0; mt < 4; ++mt) ab[mt] = h0r + (mt * 16 + lm) * HID;
        gemm_part<4, KP1>(wave * 128, keo, lm, ab, wlds, acc);
      }

      // own barrier: h1(t-1) ready (all prog1 >= t)
      if (wave == 0) {
        const unsigned needO = (unsigned)t;
        if (seenOwn < needO) {
          seenOwn = scan1(PROG1, needO);
          __builtin_amdgcn_fence(__ATOMIC_ACQUIRE, "agent");
        }
      }
      __syncthreads();

      // h-phase: K=[1024,2048) from h1(t-1)
      {
        const unsigned short* hb[4];
        const unsigned short* h1r = h1 + (size_t)((t + 1) & 1) * 65536;
#pragma unroll
        for (int mt = 0; mt < 4; ++mt) hb[mt] = h1r + (mt * 16 + lm) * HID - 1024;
        gemm_part<4, KP1>(1024 + wave * 128, keo, lm, hb, wlds, acc);
      }

      reduce_cell(acc, h1 + (size_t)(t & 1) * 65536, t);
      finish_step(t & 1, (unsigned)(t + 1), PROG1);   // prog1 = t+1
    }
  }

  // ---- full-grid join (round-based RMW tree; 2 uses, off the hot loop) ----
  auto sync_all = [&](unsigned r) {
    __builtin_amdgcn_s_waitcnt(0);
    __syncthreads();
    if (tid == 0) {
      unsigned old = __hip_atomic_fetch_add(&bar[FJBASE + (wg & 7) * 32], 1u,
                                            __ATOMIC_RELAXED, __HIP_MEMORY_SCOPE_AGENT);
      if (old == r * 32u - 1u) {
        unsigned mo = __hip_atomic_fetch_add(&bar[FJL2], 1u,
                                             __ATOMIC_RELAXED, __HIP_MEMORY_SCOPE_AGENT);
        if (mo == r * 8u - 1u)
          __hip_atomic_store(&bar[FJFLAG], r, __ATOMIC_RELAXED, __HIP_MEMORY_SCOPE_AGENT);
      }
      spin_ge(FJFLAG, r);
      __builtin_amdgcn_fence(__ATOMIC_ACQUIRE, "agent");
    }
    __syncthreads();
  };

  sync_all(1);   // all lh stores visible before FC reads

  // ===== FC: pred[64, 32000] = last_h @ fc_w^T + fc_b  (fcw f32 -> bf16 on the fly)
  const int colbase = wg * 125;                 // 256 * 125 = 32000
  const int col  = colbase + wave * 16 + lm;    // 8 waves x 16 = 128 cols
  const int colc = (col < NCLS) ? col : (NCLS - 1);
  floatx4 facc[4];
  {
    const unsigned short* ab[4];
#pragma unroll
    for (int mt = 0; mt < 4; ++mt) ab[mt] = lh + (mt * 16 + lm) * HID;
    const float* bb = fcw + (size_t)colc * HID;

#pragma unroll
    for (int mt = 0; mt < 4; ++mt) facc[mt] = (floatx4){0.f, 0.f, 0.f, 0.f};

    short8 a0[4], a1[4], b0, b1;
    auto ld = [&](short8 (&A)[4], short8& B, int kbase) {
      const int off = kbase + keo;
      float4 v0 = *(const float4*)(bb + off);
      float4 v1 = *(const float4*)(bb + off + 4);
      short8 bv;
      bv[0] = (short)f2bf(v0.x); bv[1] = (short)f2bf(v0.y);
      bv[2] = (short)f2bf(v0.z); bv[3] = (short)f2bf(v0.w);
      bv[4] = (short)f2bf(v1.x); bv[5] = (short)f2bf(v1.y);
      bv[6] = (short)f2bf(v1.z); bv[7] = (short)f2bf(v1.w);
      B = bv;
#pragma unroll
      for (int mt = 0; mt < 4; ++mt)
        A[mt] = *reinterpret_cast<const short8*>(ab[mt] + off);
    };
    ld(a0, b0, 0);
#pragma unroll
    for (int kt = 0; kt < 30; kt += 2) {
      ld(a1, b1, (kt + 1) * 32);
#pragma unroll
      for (int mt = 0; mt < 4; ++mt)
        facc[mt] = __builtin_amdgcn_mfma_f32_16x16x32_bf16(a0[mt], b0, facc[mt], 0, 0, 0);
      ld(a0, b0, (kt + 2) * 32);
#pragma unroll
      for (int mt = 0; mt < 4; ++mt)
        facc[mt] = __builtin_amdgcn_mfma_f32_16x16x32_bf16(a1[mt], b1, facc[mt], 0, 0, 0);
    }
    ld(a1, b1, 31 * 32);
#pragma unroll
    for (int mt = 0; mt < 4; ++mt)
      facc[mt] = __builtin_amdgcn_mfma_f32_16x16x32_bf16(a0[mt], b0, facc[mt], 0, 0, 0);
#pragma unroll
    for (int mt = 0; mt < 4; ++mt)
      facc[mt] = __builtin_amdgcn_mfma_f32_16x16x32_bf16(a1[mt], b1, facc[mt], 0, 0, 0);
  }

  sync_all(2);   // everyone done reading lh before stores clobber scratch

  if (col < colbase + 125) {
    const float bias = fcb[col];
#pragma unroll
    for (int mt = 0; mt < 4; ++mt)
#pragma unroll
      for (int r = 0; r < 4; ++r) {
        const int row = mt * 16 + quad * 4 + r;
        out[(size_t)row * NCLS + col] = facc[mt][r] + bias;
      }
  }
}

extern "C" void kernel_launch(void* const* d_in, const int* in_sizes, int n_in,
                              void* d_out, int out_size, void* d_ws, size_t ws_size,
                              hipStream_t stream) {
  (void)in_sizes; (void)n_in; (void)out_size; (void)ws_size;
  const int*   feat = (const int*)d_in[0];
  const float* emb  = (const float*)d_in[1];
  const float* wih0 = (const float*)d_in[2];
  const float* whh0 = (const float*)d_in[3];
  const float* bih0 = (const float*)d_in[4];
  const float* bhh0 = (const float*)d_in[5];
  const float* wih1 = (const float*)d_in[6];
  const float* whh1 = (const float*)d_in[7];
  const float* bih1 = (const float*)d_in[8];
  const float* bhh1 = (const float*)d_in[9];
  const float* fcw  = (const float*)d_in[10];
  const float* fcb  = (const float*)d_in[11];
  float*       out  = (float*)d_out;
  unsigned*    bar  = (unsigned*)d_ws;

  // zero bf16 scratch inside d_out (h0 ring x8, h1 x2, lh, xbuf x4) + prog/join words
  hipMemsetAsync(d_out, 0, 1703936, stream);
  hipMemsetAsync(d_ws, 0, 8192, stream);

  void* args[] = { &feat, &emb, &wih0, &whh0, &bih0, &bhh0, &wih1, &whh1,
                   &bih1, &bhh1, &fcw, &fcb, &out, &bar };
  hipLaunchCooperativeKernel((const void*)lstm_kernel, dim3(NWG), dim3(NTHR),
                             args, 0, stream);
}

// Round 7
// 5663.153 us; speedup vs baseline: 1.4701x; 1.0316x over previous
//
#include <hip/hip_runtime.h>

#define NWG   256
#define NTHR  512
#define TSEQ  512
#define HID   1024
#define NCLS  32000
#define KP1   2056   // padded LDS row stride (elements), layer 1 (K=2048)
#define KP0   1544   // padded LDS row stride (elements), layer 0 (K=1536)
#define RP    44     // red row stride (f32): per-16-lane-phase 2-way (free)
#define PROG0 256    // per-WG progress, layer 0: bar[PROG0 + wl*4]  (1 + steps done)
#define PROG1 1024   // per-WG progress, layer 1: bar[PROG1 + wl*4]  (steps done)
#define FJBASE 1600  // final join arrive counters (8 groups x 32 WGs)
#define FJL2   1856
#define FJFLAG 1888
#define SPIN_GUARD 10000000u   // LDS / final-join spins (~0.3 s max)
#define SCAN_GUARD 1000000u    // LLC scan spins; on expiry -> saturate (fail fast)
#define SATUR 0x7FFFFFFFu

typedef __attribute__((ext_vector_type(8))) short short8;
typedef __attribute__((ext_vector_type(4))) float floatx4;

__device__ __forceinline__ unsigned short f2bf(float f) {
  union { float f; unsigned u; } c; c.f = f;
  unsigned r = c.u + 0x7fffu + ((c.u >> 16) & 1u);
  return (unsigned short)(r >> 16);
}
__device__ __forceinline__ float sigmoidf_(float x) {
  x = fminf(30.f, fmaxf(-30.f, x));
  return 1.f / (1.f + __expf(-x));
}
__device__ __forceinline__ float tanhf_(float x) {
  x = fminf(15.f, fmaxf(-15.f, x));
  float e = __expf(2.f * x);
  return (e - 1.f) / (e + 1.f);
}
__device__ __forceinline__ void st_u32_agent(unsigned* p, unsigned v) {
  __hip_atomic_store(p, v, __ATOMIC_RELAXED, __HIP_MEMORY_SCOPE_AGENT);
}
__device__ __forceinline__ unsigned ld_u32_agent(const unsigned* p) {
  return __hip_atomic_load(p, __ATOMIC_RELAXED, __HIP_MEMORY_SCOPE_AGENT);
}

// Coherent 16B load: bypass L1/L2, read the LLC (point of coherence where the
// producers' agent-scope write-through stores land).  kt is compile-time.
__device__ __forceinline__ void ld16_sc(short8& d, const unsigned short* p, int kt) {
  switch (kt) {
  case 0:  asm volatile("global_load_dwordx4 %0, %1, off sc0 sc1"            : "=v"(d) : "v"(p)); break;
  case 1:  asm volatile("global_load_dwordx4 %0, %1, off offset:64 sc0 sc1"  : "=v"(d) : "v"(p)); break;
  case 2:  asm volatile("global_load_dwordx4 %0, %1, off offset:128 sc0 sc1" : "=v"(d) : "v"(p)); break;
  default: asm volatile("global_load_dwordx4 %0, %1, off offset:192 sc0 sc1" : "=v"(d) : "v"(p)); break;
  }
}

// Coherent-A batch GEMM phase: issue ALL A loads (one LLC-latency exposure),
// read B from LDS, then wait + sched fence (rule: MFMA must not hoist past the
// inline-asm waitcnt) and run the MFMA burst.
template <int NKT, int KPAD>
__device__ __forceinline__ void gemm_sc(
    int kb, int keo, int lm,
    const unsigned short* const (&ab)[4],
    const unsigned short* wl, floatx4 (&acc)[4][2])
{
  short8 A[NKT][4];
#pragma unroll
  for (int mt = 0; mt < 4; ++mt) {
    const unsigned short* p = ab[mt] + kb + keo;
#pragma unroll
    for (int kt = 0; kt < NKT; ++kt)
      ld16_sc(A[kt][mt], p, kt);
  }
  short8 B[NKT][2];
#pragma unroll
  for (int kt = 0; kt < NKT; ++kt) {
    const int off = kb + kt * 32 + keo;
#pragma unroll
    for (int nt = 0; nt < 2; ++nt)
      B[kt][nt] = *reinterpret_cast<const short8*>(wl + (nt * 16 + lm) * KPAD + off);
  }
  asm volatile("s_waitcnt vmcnt(0)" ::: "memory");
  __builtin_amdgcn_sched_barrier(0);
#pragma unroll
  for (int kt = 0; kt < NKT; ++kt)
#pragma unroll
    for (int mt = 0; mt < 4; ++mt)
#pragma unroll
      for (int nt = 0; nt < 2; ++nt)
        acc[mt][nt] = __builtin_amdgcn_mfma_f32_16x16x32_bf16(A[kt][mt], B[kt][nt], acc[mt][nt], 0, 0, 0);
}

__global__ void __launch_bounds__(NTHR, 1)
lstm_kernel(const int* __restrict__ feat,
            const float* __restrict__ emb,
            const float* __restrict__ wih0, const float* __restrict__ whh0,
            const float* __restrict__ bih0, const float* __restrict__ bhh0,
            const float* __restrict__ wih1, const float* __restrict__ whh1,
            const float* __restrict__ bih1, const float* __restrict__ bhh1,
            const float* __restrict__ fcw, const float* __restrict__ fcb,
            float* __restrict__ out,
            unsigned* __restrict__ bar)
{
  const int tid  = threadIdx.x;
  const int wg   = blockIdx.x;
  const int wave = tid >> 6;
  const int lane = tid & 63;
  const int quad = lane >> 4;
  const int lm   = lane & 15;
  const int keo  = quad * 8;

  // bf16 scratch inside d_out (f32 [64,32000] = 8.19 MB); FC overwrites at end.
  unsigned short* sc   = (unsigned short*)out;
  unsigned short* h0   = sc;              // 8-slot ring x [64][1024]  (layer-0 out)
  unsigned short* h1   = sc + 524288;     // 2 x [64][1024]
  unsigned short* lh   = sc + 655360;     // [64][1024]
  unsigned short* xbuf = sc + 720896;     // 4-slot ring x [64][512]  (staged x, bf16)

  const int layer = (wg >= 128) ? 1 : 0;
  const int wl_id = wg & 127;
  const int jb = wl_id * 8;               // this WG owns H-columns [jb, jb+8)

  __shared__ unsigned short wlds[32 * KP1];  // this WG's weights, bf16
  __shared__ float red[4][32][RP];           // K-split partials
  __shared__ int   sl[64];
  __shared__ unsigned sdone[2];              // per-parity "cell stores drained" count

  if (tid < 2) sdone[tid] = 0;

  // ---- one-time: weights f32 -> bf16 -> LDS  (rows r: gate=r>>3, col=jb+(r&7)) ----
  {
    const float* wih = layer ? wih1 : wih0;
    const float* whh = layer ? whh1 : whh0;
    const int KX   = layer ? 1024 : 512;
    const int KTOT = layer ? 2048 : 1536;
    const int KPAD = layer ? KP1 : KP0;
    for (int r = 0; r < 32; ++r) {
      const int gr = (r >> 3) * HID + jb + (r & 7);
      for (int e4 = tid; e4 < (KTOT >> 2); e4 += NTHR) {
        const int k = e4 * 4;
        float4 v = (k < KX) ? *(const float4*)(wih + (size_t)gr * KX + k)
                            : *(const float4*)(whh + (size_t)gr * 1024 + (k - KX));
        ushort4 u; u.x = f2bf(v.x); u.y = f2bf(v.y); u.z = f2bf(v.z); u.w = f2bf(v.w);
        *(ushort4*)(wlds + r * KPAD + k) = u;
      }
    }
    if (layer && tid < 64) {   // seq_lens
      int cnt = 0;
      const int* fr = feat + tid * TSEQ;
      for (int k = 0; k < TSEQ; k += 4)
        cnt += (fr[k] != 31999) + (fr[k + 1] != 31999) +
               (fr[k + 2] != 31999) + (fr[k + 3] != 31999);
      int v = cnt - 1; if (v < 0) v = 0;
      sl[tid] = v;
    }
  }
  __syncthreads();

  // ---- per-cell-thread persistent state (tid<256: b = half*32 + (tid>>3), jl = tid&7)
  float bsum[4];
  float cv[2] = {0.f, 0.f};
  int   slv[2] = {0, 0};
  const int jl_c = tid & 7;
  const int bl_c = tid >> 3;     // 0..31 for tid<256
  if (tid < 256) {
    const float* bih = layer ? bih1 : bih0;
    const float* bhh = layer ? bhh1 : bhh0;
    const int gj = jb + jl_c;
#pragma unroll
    for (int g = 0; g < 4; ++g) bsum[g] = bih[g * HID + gj] + bhh[g * HID + gj];
    if (layer) { slv[0] = sl[bl_c]; slv[1] = sl[32 + bl_c]; }
  }

  // ---- wave-cooperative scans over 128 per-WG progress words (no RMW).
  //      No acquire fence needed: all cross-WG data reads are sc0sc1-coherent.
  //      FAIL-FAST: on watchdog expiry return SATUR so all later waits skip.
  auto scan1 = [&](int base, unsigned need) -> unsigned {
    unsigned g = 0, a0, a1;
    bool dead = false;
    for (;;) {
      a0 = ld_u32_agent(&bar[base + lane * 4]);
      a1 = ld_u32_agent(&bar[base + (64 + lane) * 4]);
      if (__all(a0 >= need && a1 >= need)) break;
      __builtin_amdgcn_s_sleep(1);
      if (++g > SCAN_GUARD) { dead = true; break; }
    }
    if (dead) return SATUR;
    unsigned m = a0 < a1 ? a0 : a1;
#pragma unroll
    for (int off = 32; off; off >>= 1) {
      unsigned o = (unsigned)__shfl_xor((int)m, off, 64);
      m = o < m ? o : m;
    }
    return m;
  };
  auto scan2 = [&](int baseA, unsigned needA, int baseB, unsigned needB,
                   unsigned& minA, unsigned& minB) {
    unsigned g = 0, a0, a1, b0, b1;
    bool dead = false;
    for (;;) {
      a0 = ld_u32_agent(&bar[baseA + lane * 4]);
      a1 = ld_u32_agent(&bar[baseA + (64 + lane) * 4]);
      b0 = ld_u32_agent(&bar[baseB + lane * 4]);
      b1 = ld_u32_agent(&bar[baseB + (64 + lane) * 4]);
      if (__all(a0 >= needA && a1 >= needA && b0 >= needB && b1 >= needB)) break;
      __builtin_amdgcn_s_sleep(1);
      if (++g > SCAN_GUARD) { dead = true; break; }
    }
    if (dead) { minA = SATUR; minB = SATUR; return; }
    unsigned ma = a0 < a1 ? a0 : a1;
    unsigned mb = b0 < b1 ? b0 : b1;
#pragma unroll
    for (int off = 32; off; off >>= 1) {
      unsigned oa = (unsigned)__shfl_xor((int)ma, off, 64); ma = oa < ma ? oa : ma;
      unsigned ob = (unsigned)__shfl_xor((int)mb, off, 64); mb = ob < mb ? ob : mb;
    }
    minA = ma; minB = mb;
  };
  auto spin_ge = [&](int idx, unsigned need) {   // final-join only
    unsigned g = 0;
    while (ld_u32_agent(&bar[idx]) < need) {
      __builtin_amdgcn_s_sleep(1);
      if (++g > SPIN_GUARD) break;
    }
  };

  // ---- reduction + fused cell update (round-2-proven) ----
  auto reduce_cell = [&](floatx4 (&acc)[4][2], unsigned short* hw, int t) {
#pragma unroll
    for (int h = 0; h < 2; ++h) {
      if (wave < 4) {
#pragma unroll
        for (int mi = 0; mi < 2; ++mi)
#pragma unroll
          for (int nt = 0; nt < 2; ++nt)
#pragma unroll
            for (int r = 0; r < 4; ++r)
              red[wave][mi * 16 + quad * 4 + r][nt * 16 + lm] = acc[2 * h + mi][nt][r];
      }
      __syncthreads();
      if (wave >= 4) {
#pragma unroll
        for (int mi = 0; mi < 2; ++mi)
#pragma unroll
          for (int nt = 0; nt < 2; ++nt)
#pragma unroll
            for (int r = 0; r < 4; ++r)
              red[wave - 4][mi * 16 + quad * 4 + r][nt * 16 + lm] += acc[2 * h + mi][nt][r];
      }
      __syncthreads();
      if (tid < 256) {
        const int b = h * 32 + bl_c;
        float g0 = bsum[0], g1 = bsum[1], g2 = bsum[2], g3 = bsum[3];
#pragma unroll
        for (int v = 0; v < 4; ++v) {
          g0 += red[v][bl_c][jl_c];
          g1 += red[v][bl_c][8 + jl_c];
          g2 += red[v][bl_c][16 + jl_c];
          g3 += red[v][bl_c][24 + jl_c];
        }
        const float ig = sigmoidf_(g0);
        const float fg = sigmoidf_(g1);
        const float gg = tanhf_(g2);
        const float og = sigmoidf_(g3);
        const float cn = fg * cv[h] + ig * gg;
        cv[h] = cn;
        const float hn = og * tanhf_(cn);
        unsigned my = f2bf(hn);
        unsigned ov = (unsigned)__shfl_xor((int)my, 1, 64);
        if ((tid & 1) == 0) {
          const unsigned packed = my | (ov << 16);
          st_u32_agent((unsigned*)(hw + b * HID + jb + jl_c), packed);
          if (layer && t == slv[h])
            st_u32_agent((unsigned*)(lh + b * HID + jb + jl_c), packed);
        }
      }
      if (h == 0) __syncthreads();
    }
  };

  // ---- publish progress: waves 0-3 drain + LDS-signal; wave 7 plain-stores
  //      this WG's OWN progress word (no RMW, no cacheline contention).
  auto finish_step = [&](int par, unsigned r, int pbase) {
    if (wave < 4) {
      __builtin_amdgcn_s_waitcnt(0);   // drain h/lh/xbuf agent stores of this wave
      if (lane == 0)
        __hip_atomic_fetch_add(&sdone[par], 1u, __ATOMIC_RELAXED, __HIP_MEMORY_SCOPE_WORKGROUP);
    } else if (wave == 7 && lane == 0) {
      unsigned g = 0;
      while (__hip_atomic_load(&sdone[par], __ATOMIC_RELAXED, __HIP_MEMORY_SCOPE_WORKGROUP) < 4u)
        if (++g > SPIN_GUARD) break;
      __hip_atomic_store(&sdone[par], 0u, __ATOMIC_RELAXED, __HIP_MEMORY_SCOPE_WORKGROUP);
      st_u32_agent(&bar[pbase + wl_id * 4], r);
    }
  };

  if (!layer) {
    // =========================== LAYER 0 ===========================
    // prologue: stage x(0), x(1); publish prog0 = 1; wait domain
    if (tid < 256) {
      const int b = wl_id >> 1;
      const int off = (wl_id & 1) * 256 + tid;
#pragma unroll
      for (int tt = 0; tt < 2; ++tt) {
        unsigned xv = f2bf(emb[(size_t)feat[b * TSEQ + tt] * 512 + off]);
        unsigned ov = (unsigned)__shfl_xor((int)xv, 1, 64);
        if ((tid & 1) == 0)
          st_u32_agent((unsigned*)(xbuf + tt * 32768 + b * 512 + off), xv | (ov << 16));
      }
    }
    __builtin_amdgcn_s_waitcnt(0);
    __syncthreads();
    if (wave == 7 && lane == 0) st_u32_agent(&bar[PROG0 + wl_id * 4], 1u);
    unsigned seenOwn = 1, seenRing = 0;   // wave-0 caches (uniform)
    if (wave == 0) seenOwn = scan1(PROG0, 1u);
    __syncthreads();

    for (int t = 0; t < TSEQ; ++t) {
      // stage x(t+2) into slot (t+2)&3 (readers gated by prog0 >= t+2)
      if (t + 2 < TSEQ && tid < 256) {
        const int b = wl_id >> 1;
        const int off = (wl_id & 1) * 256 + tid;
        unsigned xv = f2bf(emb[(size_t)feat[b * TSEQ + (t + 2)] * 512 + off]);
        unsigned ov = (unsigned)__shfl_xor((int)xv, 1, 64);
        if ((tid & 1) == 0)
          st_u32_agent((unsigned*)(xbuf + ((t + 2) & 3) * 32768 + b * 512 + off), xv | (ov << 16));
      }

      floatx4 acc[4][2];
#pragma unroll
      for (int mt = 0; mt < 4; ++mt)
#pragma unroll
        for (int nt = 0; nt < 2; ++nt)
          acc[mt][nt] = (floatx4){0.f, 0.f, 0.f, 0.f};

      // x-phase: K=[0,512) from xbuf slot t&3 — zero sync at step top
      // (x(t) visibility: prog0 >= t observed at step t-1's own-scan).
      {
        const unsigned short* ab[4];
        const unsigned short* xq = xbuf + (size_t)(t & 3) * 32768;
#pragma unroll
        for (int mt = 0; mt < 4; ++mt) ab[mt] = xq + (mt * 16 + lm) * 512;
        gemm_sc<2, KP0>(wave * 64, keo, lm, ab, wlds, acc);
      }

      // own barrier: h0(t-1) ready (all prog0 >= t+1); ring: L1 consumed h0(t-8)
      if (wave == 0) {
        const unsigned needO = (unsigned)(t + 1);
        const unsigned needR = (t >= 8) ? (unsigned)(t - 7) : 0u;
        if (seenOwn < needO || seenRing < needR)
          scan2(PROG0, needO, PROG1, needR, seenOwn, seenRing);
      }
      __syncthreads();

      // h-phase: K=[512,1536) from h0(t-1)
      {
        const unsigned short* hb[4];
        const unsigned short* h0r = h0 + (size_t)((t + 7) & 7) * 65536;
#pragma unroll
        for (int mt = 0; mt < 4; ++mt) hb[mt] = h0r + (mt * 16 + lm) * HID - 512;
        gemm_sc<4, KP0>(512 + wave * 128, keo, lm, hb, wlds, acc);
      }

      reduce_cell(acc, h0 + (size_t)(t & 7) * 65536, t);
      finish_step(t & 1, (unsigned)(t + 2), PROG0);   // prog0 = t+2
    }
  } else {
    // =========================== LAYER 1 ===========================
    unsigned seenX = 0;      // per-wave cache (uniform within wave)
    unsigned seenOwn = 0;    // wave-0 cache
    for (int t = 0; t < TSEQ; ++t) {
      // cross dep: h0(t) ready (all prog0 >= t+2); per-wave scan, cached by min
      const unsigned needX = (unsigned)(t + 2);
      if (seenX < needX) seenX = scan1(PROG0, needX);

      floatx4 acc[4][2];
#pragma unroll
      for (int mt = 0; mt < 4; ++mt)
#pragma unroll
        for (int nt = 0; nt < 2; ++nt)
          acc[mt][nt] = (floatx4){0.f, 0.f, 0.f, 0.f};

      // x-phase: K=[0,1024) from h0(t) — overlaps own-domain stragglers
      {
        const unsigned short* ab[4];
        const unsigned short* h0r = h0 + (size_t)(t & 7) * 65536;
#pragma unroll
        for (int mt = 0; mt < 4; ++mt) ab[mt] = h0r + (mt * 16 + lm) * HID;
        gemm_sc<4, KP1>(wave * 128, keo, lm, ab, wlds, acc);
      }

      // own barrier: h1(t-1) ready (all prog1 >= t)
      if (wave == 0) {
        const unsigned needO = (unsigned)t;
        if (seenOwn < needO) seenOwn = scan1(PROG1, needO);
      }
      __syncthreads();

      // h-phase: K=[1024,2048) from h1(t-1)
      {
        const unsigned short* hb[4];
        const unsigned short* h1r = h1 + (size_t)((t + 1) & 1) * 65536;
#pragma unroll
        for (int mt = 0; mt < 4; ++mt) hb[mt] = h1r + (mt * 16 + lm) * HID - 1024;
        gemm_sc<4, KP1>(1024 + wave * 128, keo, lm, hb, wlds, acc);
      }

      reduce_cell(acc, h1 + (size_t)(t & 1) * 65536, t);
      finish_step(t & 1, (unsigned)(t + 1), PROG1);   // prog1 = t+1
    }
  }

  // ---- full-grid join (round-based RMW tree; 2 uses, off the hot loop).
  //      Keeps its acquire fence: FC reads lh with normal cached loads.
  auto sync_all = [&](unsigned r) {
    __builtin_amdgcn_s_waitcnt(0);
    __syncthreads();
    if (tid == 0) {
      unsigned old = __hip_atomic_fetch_add(&bar[FJBASE + (wg & 7) * 32], 1u,
                                            __ATOMIC_RELAXED, __HIP_MEMORY_SCOPE_AGENT);
      if (old == r * 32u - 1u) {
        unsigned mo = __hip_atomic_fetch_add(&bar[FJL2], 1u,
                                             __ATOMIC_RELAXED, __HIP_MEMORY_SCOPE_AGENT);
        if (mo == r * 8u - 1u)
          __hip_atomic_store(&bar[FJFLAG], r, __ATOMIC_RELAXED, __HIP_MEMORY_SCOPE_AGENT);
      }
      spin_ge(FJFLAG, r);
      __builtin_amdgcn_fence(__ATOMIC_ACQUIRE, "agent");
    }
    __syncthreads();
  };

  sync_all(1);   // all lh stores visible before FC reads

  // ===== FC: pred[64, 32000] = last_h @ fc_w^T + fc_b  (fcw f32 -> bf16 on the fly)
  const int colbase = wg * 125;                 // 256 * 125 = 32000
  const int col  = colbase + wave * 16 + lm;    // 8 waves x 16 = 128 cols
  const int colc = (col < NCLS) ? col : (NCLS - 1);
  floatx4 facc[4];
  {
    const unsigned short* ab[4];
#pragma unroll
    for (int mt = 0; mt < 4; ++mt) ab[mt] = lh + (mt * 16 + lm) * HID;
    const float* bb = fcw + (size_t)colc * HID;

#pragma unroll
    for (int mt = 0; mt < 4; ++mt) facc[mt] = (floatx4){0.f, 0.f, 0.f, 0.f};

    short8 a0[4], a1[4], b0, b1;
    auto ld = [&](short8 (&A)[4], short8& B, int kbase) {
      const int off = kbase + keo;
      float4 v0 = *(const float4*)(bb + off);
      float4 v1 = *(const float4*)(bb + off + 4);
      short8 bv;
      bv[0] = (short)f2bf(v0.x); bv[1] = (short)f2bf(v0.y);
      bv[2] = (short)f2bf(v0.z); bv[3] = (short)f2bf(v0.w);
      bv[4] = (short)f2bf(v1.x); bv[5] = (short)f2bf(v1.y);
      bv[6] = (short)f2bf(v1.z); bv[7] = (short)f2bf(v1.w);
      B = bv;
#pragma unroll
      for (int mt = 0; mt < 4; ++mt)
        A[mt] = *reinterpret_cast<const short8*>(ab[mt] + off);
    };
    ld(a0, b0, 0);
#pragma unroll
    for (int kt = 0; kt < 30; kt += 2) {
      ld(a1, b1, (kt + 1) * 32);
#pragma unroll
      for (int mt = 0; mt < 4; ++mt)
        facc[mt] = __builtin_amdgcn_mfma_f32_16x16x32_bf16(a0[mt], b0, facc[mt], 0, 0, 0);
      ld(a0, b0, (kt + 2) * 32);
#pragma unroll
      for (int mt = 0; mt < 4; ++mt)
        facc[mt] = __builtin_amdgcn_mfma_f32_16x16x32_bf16(a1[mt], b1, facc[mt], 0, 0, 0);
    }
    ld(a1, b1, 31 * 32);
#pragma unroll
    for (int mt = 0; mt < 4; ++mt)
      facc[mt] = __builtin_amdgcn_mfma_f32_16x16x32_bf16(a0[mt], b0, facc[mt], 0, 0, 0);
#pragma unroll
    for (int mt = 0; mt < 4; ++mt)
      facc[mt] = __builtin_amdgcn_mfma_f32_16x16x32_bf16(a1[mt], b1, facc[mt], 0, 0, 0);
  }

  sync_all(2);   // everyone done reading lh before stores clobber scratch

  if (col < colbase + 125) {
    const float bias = fcb[col];
#pragma unroll
    for (int mt = 0; mt < 4; ++mt)
#pragma unroll
      for (int r = 0; r < 4; ++r) {
        const int row = mt * 16 + quad * 4 + r;
        out[(size_t)row * NCLS + col] = facc[mt][r] + bias;
      }
  }
}

extern "C" void kernel_launch(void* const* d_in, const int* in_sizes, int n_in,
                              void* d_out, int out_size, void* d_ws, size_t ws_size,
                              hipStream_t stream) {
  (void)in_sizes; (void)n_in; (void)out_size; (void)ws_size;
  const int*   feat = (const int*)d_in[0];
  const float* emb  = (const float*)d_in[1];
  const float* wih0 = (const float*)d_in[2];
  const float* whh0 = (const float*)d_in[3];
  const float* bih0 = (const float*)d_in[4];
  const float* bhh0 = (const float*)d_in[5];
  const float* wih1 = (const float*)d_in[6];
  const float* whh1 = (const float*)d_in[7];
  const float* bih1 = (const float*)d_in[8];
  const float* bhh1 = (const float*)d_in[9];
  const float* fcw  = (const float*)d_in[10];
  const float* fcb  = (const float*)d_in[11];
  float*       out  = (float*)d_out;
  unsigned*    bar  = (unsigned*)d_ws;

  // zero bf16 scratch inside d_out (h0 ring x8, h1 x2, lh, xbuf x4) + prog/join words
  hipMemsetAsync(d_out, 0, 1703936, stream);
  hipMemsetAsync(d_ws, 0, 8192, stream);

  void* args[] = { &feat, &emb, &wih0, &whh0, &bih0, &bhh0, &wih1, &whh1,
                   &bih1, &bhh1, &fcw, &fcb, &out, &bar };
  hipLaunchCooperativeKernel((const void*)lstm_kernel, dim3(NWG), dim3(NTHR),
                             args, 0, stream);
}